// Round 5
// baseline (790.946 us; speedup 1.0000x reference)
//
#include <hip/hip_runtime.h>
#include <cmath>

#define B_ROWS 16384
#define IN_DIM 784
#define N_HID  2000
#define K_WIN  200

// ---------------------------------------------------------------------------
// Phase 0a: boost[i] = expf(0.1f - duty[i])
// ---------------------------------------------------------------------------
__global__ __launch_bounds__(256) void boost_kernel(const float* __restrict__ duty,
                                                    float* __restrict__ boost) {
    int i = blockIdx.x * 256 + threadIdx.x;
    if (i < N_HID) boost[i] = expf(0.1f - duty[i]);
}

// ---------------------------------------------------------------------------
// Phase 0b: w2t[i*12 + c] = w2[c*2000 + i]
// ---------------------------------------------------------------------------
__global__ __launch_bounds__(256) void w2t_kernel(const float* __restrict__ w2,
                                                  float* __restrict__ w2t) {
    int t = blockIdx.x * 256 + threadIdx.x;
    if (t < N_HID * 10) {
        int i = t / 10, c = t - i * 10;
        w2t[i * 12 + c] = w2[c * N_HID + i];
    }
}

// ---------------------------------------------------------------------------
// Phase 1: h = x @ W1^T + b1, fp32.  WAVE-AUTONOMOUS: each wave computes a
// private 64x64 tile (8x8 microtile/lane, split 4+4) from a PRIVATE LDS
// staging region -> ZERO __syncthreads in the whole kernel.  Within a wave,
// DS ops are in-order and compiler lgkmcnt covers RAW; no cross-wave LDS
// sharing exists.  Register prefetch pipeline per wave (round-4 style).
// Per-output k-summation order (k=0..783 ascending, fmaf chain) identical to
// rounds 2-4 -> h bit-identical.
// ---------------------------------------------------------------------------
__global__ __launch_bounds__(256) void gemm_fp32_kernel(const float* __restrict__ x,
                                                        const float* __restrict__ w1,
                                                        const float* __restrict__ b1,
                                                        float* __restrict__ h) {
    __shared__ float As[4][16][68] __attribute__((aligned(16)));   // [wave][k][m]
    __shared__ float Bs[4][16][68] __attribute__((aligned(16)));   // [wave][k][n]
    const int tid  = threadIdx.x;
    const int wv   = tid >> 6;
    const int lane = tid & 63;
    const int m0 = blockIdx.y * 128 + (wv >> 1) * 64;   // wave m-origin
    const int n0 = blockIdx.x * 128 + (wv & 1) * 64;    // wave n-origin
    const int tx = lane & 7;          // n microtile
    const int ty = lane >> 3;         // m microtile
    const int sr = lane >> 2;         // 0..15 staging row base
    const int sc = (lane & 3) << 2;   // 0,4,8,12 staging k-offset

    float (*A)[68]  = As[wv];
    float (*Bv)[68] = Bs[wv];

    // staging row indices (4 passes of 16 rows); B rows clamped, stores guarded
    const float* xbase = x + (size_t)(m0 + sr) * IN_DIM + sc;
    const float* wbase[4];
    #pragma unroll
    for (int p = 0; p < 4; ++p) {
        int nb = n0 + sr + p * 16;
        if (nb > N_HID - 1) nb = N_HID - 1;
        wbase[p] = w1 + (size_t)nb * IN_DIM + sc;
    }

    float4 pa[4], pb[4];
    #pragma unroll
    for (int p = 0; p < 4; ++p) {
        pa[p] = *(const float4*)(xbase + (size_t)p * 16 * IN_DIM);
        pb[p] = *(const float4*)(wbase[p]);
    }

    float acc[8][8] = {};

    for (int k0 = 0; k0 < IN_DIM; k0 += 16) {
        // stage prefetched regs into this wave's private LDS region
        #pragma unroll
        for (int p = 0; p < 4; ++p) {
            const int row = sr + p * 16;
            A[sc + 0][row] = pa[p].x;  A[sc + 1][row] = pa[p].y;
            A[sc + 2][row] = pa[p].z;  A[sc + 3][row] = pa[p].w;
            Bv[sc + 0][row] = pb[p].x; Bv[sc + 1][row] = pb[p].y;
            Bv[sc + 2][row] = pb[p].z; Bv[sc + 3][row] = pb[p].w;
        }

        // issue next tile's global loads; latency hides under the FMA loop
        const int kn = (k0 + 16 < IN_DIM) ? (k0 + 16) : 0;  // last-iter dummy
        #pragma unroll
        for (int p = 0; p < 4; ++p) {
            pa[p] = *(const float4*)(xbase + kn + (size_t)p * 16 * IN_DIM);
            pb[p] = *(const float4*)(wbase[p] + kn);
        }

        #pragma unroll
        for (int kk = 0; kk < 16; ++kk) {
            float a[8], b[8];
            *(float4*)&a[0] = *(const float4*)&A[kk][ty * 4];
            *(float4*)&a[4] = *(const float4*)&A[kk][32 + ty * 4];
            *(float4*)&b[0] = *(const float4*)&Bv[kk][tx * 4];
            *(float4*)&b[4] = *(const float4*)&Bv[kk][32 + tx * 4];
            #pragma unroll
            for (int i = 0; i < 8; ++i)
                #pragma unroll
                for (int j = 0; j < 8; ++j)
                    acc[i][j] = fmaf(a[i], b[j], acc[i][j]);
        }
    }

    #pragma unroll
    for (int i = 0; i < 8; ++i) {
        const int m = m0 + ((i < 4) ? (ty * 4 + i) : (32 + ty * 4 + (i - 4)));
        float* hrow = h + (size_t)m * N_HID;
        const int nlo = n0 + tx * 4;
        const int nhi = n0 + 32 + tx * 4;
        if (nlo + 3 < N_HID) {
            float4 v;
            v.x = acc[i][0] + b1[nlo + 0];
            v.y = acc[i][1] + b1[nlo + 1];
            v.z = acc[i][2] + b1[nlo + 2];
            v.w = acc[i][3] + b1[nlo + 3];
            *(float4*)(hrow + nlo) = v;
        } else {
            #pragma unroll
            for (int j = 0; j < 4; ++j)
                if (nlo + j < N_HID) hrow[nlo + j] = acc[i][j] + b1[nlo + j];
        }
        if (nhi + 3 < N_HID) {
            float4 w;
            w.x = acc[i][4] + b1[nhi + 0];
            w.y = acc[i][5] + b1[nhi + 1];
            w.z = acc[i][6] + b1[nhi + 2];
            w.w = acc[i][7] + b1[nhi + 3];
            *(float4*)(hrow + nhi) = w;
        } else {
            #pragma unroll
            for (int j = 0; j < 4; ++j)
                if (nhi + j < N_HID) hrow[nhi + j] = acc[i][4 + j] + b1[nhi + j];
        }
    }
}

// ---------------------------------------------------------------------------
// Phase 2: one row per wave, zero __syncthreads (unchanged from round 3/4).
// ---------------------------------------------------------------------------
__global__ __launch_bounds__(256) void topk_logits_kernel(const float* __restrict__ h,
                                                          const float* __restrict__ boost,
                                                          const float* __restrict__ w2t,
                                                          const float* __restrict__ b2,
                                                          float* __restrict__ out) {
    __shared__ unsigned shist[4 * 256] __attribute__((aligned(16)));
    const int wv   = threadIdx.x >> 6;
    const int lane = threadIdx.x & 63;
    const int row  = blockIdx.x * 4 + wv;
    unsigned* hist = &shist[wv * 256];

    const float* hrow = h + (size_t)row * N_HID;
    float4 hreg[8];
    unsigned key[8][4];

    #pragma unroll
    for (int s = 0; s < 8; ++s) {
        const int idx4 = s * 64 + lane;
        if (idx4 < N_HID / 4) {
            float4 hv = *(const float4*)(hrow + idx4 * 4);
            float4 bv = *(const float4*)(boost + idx4 * 4);
            hreg[s] = hv;
            unsigned u0 = __float_as_uint(hv.x * bv.x);
            unsigned u1 = __float_as_uint(hv.y * bv.y);
            unsigned u2 = __float_as_uint(hv.z * bv.z);
            unsigned u3 = __float_as_uint(hv.w * bv.w);
            key[s][0] = (u0 >> 31) ? ~u0 : (u0 | 0x80000000u);
            key[s][1] = (u1 >> 31) ? ~u1 : (u1 | 0x80000000u);
            key[s][2] = (u2 >> 31) ? ~u2 : (u2 | 0x80000000u);
            key[s][3] = (u3 >> 31) ? ~u3 : (u3 | 0x80000000u);
        } else {
            hreg[s] = make_float4(0.f, 0.f, 0.f, 0.f);
            key[s][0] = key[s][1] = key[s][2] = key[s][3] = 0u;
        }
    }

    unsigned pref = 0u;
    int r = K_WIN;

    #pragma unroll
    for (int pass = 3; pass >= 0; --pass) {
        const int shift = pass * 8;
        const unsigned himask = (pass == 3) ? 0u : (0xFFFFFFFFu << (shift + 8));
        hist[lane] = 0u; hist[lane + 64] = 0u; hist[lane + 128] = 0u; hist[lane + 192] = 0u;
        __builtin_amdgcn_wave_barrier();
        #pragma unroll
        for (int s = 0; s < 8; ++s)
            #pragma unroll
            for (int j = 0; j < 4; ++j) {
                unsigned k = key[s][j];
                if (((k ^ pref) & himask) == 0u)
                    atomicAdd(&hist[(k >> shift) & 255u], 1u);
            }
        __builtin_amdgcn_wave_barrier();
        uint4 hv = *(const uint4*)&hist[lane * 4];
        unsigned tot = hv.x + hv.y + hv.z + hv.w;
        unsigned run = tot;
        #pragma unroll
        for (int off = 1; off < 64; off <<= 1) {
            unsigned t = (unsigned)__shfl_down((int)run, off);
            if (lane + off < 64) run += t;
        }
        const int above = (int)(run - tot);
        const int i3 = above + (int)hv.w;
        const int i2 = i3 + (int)hv.z;
        const int i1 = i2 + (int)hv.y;
        const int i0 = i1 + (int)hv.x;
        int fq = -1, fex = 0;
        if (i0 >= r && i1 < r)    { fq = 0; fex = i1; }
        if (i1 >= r && i2 < r)    { fq = 1; fex = i2; }
        if (i2 >= r && i3 < r)    { fq = 2; fex = i3; }
        if (i3 >= r && above < r) { fq = 3; fex = above; }
        unsigned long long fm = __ballot(fq >= 0);
        int src = __builtin_ctzll(fm);
        unsigned pack = (fq >= 0)
            ? (((unsigned)(lane * 4 + fq) << 16) | (unsigned)(r - fex)) : 0u;
        pack = (unsigned)__shfl((int)pack, src);
        pref |= (pack >> 16) << shift;
        r = (int)(pack & 0xFFFFu);
    }

    const unsigned tkey = pref;
    const int take_eq = r;

    unsigned winm = 0u;
    int run_eq = 0;
    #pragma unroll
    for (int s = 0; s < 8; ++s) {
        bool gt[4], eq[4];
        #pragma unroll
        for (int j = 0; j < 4; ++j) {
            unsigned k = key[s][j];
            gt[j] = (k > tkey);
            eq[j] = (k == tkey);
        }
        unsigned long long em0 = __ballot(eq[0]);
        unsigned long long em1 = __ballot(eq[1]);
        unsigned long long em2 = __ballot(eq[2]);
        unsigned long long em3 = __ballot(eq[3]);
        const unsigned long long lt = (1ull << lane) - 1ull;
        const int base_lt = __popcll(em0 & lt) + __popcll(em1 & lt) +
                            __popcll(em2 & lt) + __popcll(em3 & lt);
        int own = 0;
        #pragma unroll
        for (int j = 0; j < 4; ++j) {
            if (gt[j]) winm |= 1u << (s * 4 + j);
            else if (eq[j]) {
                if (run_eq + base_lt + own < take_eq) winm |= 1u << (s * 4 + j);
                ++own;
            }
        }
        run_eq += __popcll(em0) + __popcll(em1) + __popcll(em2) + __popcll(em3);
    }

    float l[10];
    #pragma unroll
    for (int cc = 0; cc < 10; ++cc) l[cc] = 0.f;
    #pragma unroll
    for (int s = 0; s < 8; ++s) {
        const int idx4 = s * 64 + lane;
        const float* hp = (const float*)&hreg[s];
        #pragma unroll
        for (int j = 0; j < 4; ++j) {
            if (winm & (1u << (s * 4 + j))) {
                const float hv = hp[j];
                const float* wr = w2t + (size_t)(idx4 * 4 + j) * 12;
                float4 wa = *(const float4*)wr;
                float4 wb = *(const float4*)(wr + 4);
                float2 wc = *(const float2*)(wr + 8);
                l[0] = fmaf(hv, wa.x, l[0]);
                l[1] = fmaf(hv, wa.y, l[1]);
                l[2] = fmaf(hv, wa.z, l[2]);
                l[3] = fmaf(hv, wa.w, l[3]);
                l[4] = fmaf(hv, wb.x, l[4]);
                l[5] = fmaf(hv, wb.y, l[5]);
                l[6] = fmaf(hv, wb.z, l[6]);
                l[7] = fmaf(hv, wb.w, l[7]);
                l[8] = fmaf(hv, wc.x, l[8]);
                l[9] = fmaf(hv, wc.y, l[9]);
            }
        }
    }
    #pragma unroll
    for (int off = 32; off > 0; off >>= 1)
        #pragma unroll
        for (int cc = 0; cc < 10; ++cc)
            l[cc] += __shfl_down(l[cc], off);

    if (lane == 0) {
        float lg[10];
        #pragma unroll
        for (int cc = 0; cc < 10; ++cc) lg[cc] = l[cc] + b2[cc];
        float mx = lg[0];
        #pragma unroll
        for (int cc = 1; cc < 10; ++cc) mx = fmaxf(mx, lg[cc]);
        float s = 0.f;
        #pragma unroll
        for (int cc = 0; cc < 10; ++cc) s += expf(lg[cc] - mx);
        const float lse = mx + logf(s);
        float* orow = out + (size_t)row * 10;
        #pragma unroll
        for (int cc = 0; cc < 10; ++cc) orow[cc] = lg[cc] - lse;
    }
}

// ---------------------------------------------------------------------------
extern "C" void kernel_launch(void* const* d_in, const int* in_sizes, int n_in,
                              void* d_out, int out_size, void* d_ws, size_t ws_size,
                              hipStream_t stream) {
    const float* x    = (const float*)d_in[0];
    const float* w1   = (const float*)d_in[1];
    const float* b1   = (const float*)d_in[2];
    const float* w2   = (const float*)d_in[3];
    const float* b2   = (const float*)d_in[4];
    const float* duty = (const float*)d_in[5];
    float* out = (float*)d_out;

    const size_t hbytes = (size_t)B_ROWS * N_HID * sizeof(float);  // 131.072 MB
    float* h     = (float*)d_ws;
    float* boost = (float*)((char*)d_ws + hbytes);                 // 8 KB
    float* w2t   = (float*)((char*)d_ws + hbytes + 8192);          // 96 KB

    boost_kernel<<<8, 256, 0, stream>>>(duty, boost);
    w2t_kernel<<<(N_HID * 10 + 255) / 256, 256, 0, stream>>>(w2, w2t);
    gemm_fp32_kernel<<<dim3(16, 128), 256, 0, stream>>>(x, w1, b1, h);
    topk_logits_kernel<<<B_ROWS / 4, 256, 0, stream>>>(h, boost, w2t, b2, out);
}

// Round 6
// 774.761 us; speedup vs baseline: 1.0209x; 1.0209x over previous
//
#include <hip/hip_runtime.h>
#include <cmath>

#define B_ROWS 16384
#define IN_DIM 784
#define N_HID  2000
#define K_WIN  200

// ---------------------------------------------------------------------------
// Phase 0a: boost[i] = expf(0.1f - duty[i])
// ---------------------------------------------------------------------------
__global__ __launch_bounds__(256) void boost_kernel(const float* __restrict__ duty,
                                                    float* __restrict__ boost) {
    int i = blockIdx.x * 256 + threadIdx.x;
    if (i < N_HID) boost[i] = expf(0.1f - duty[i]);
}

// ---------------------------------------------------------------------------
// Phase 0b: w2t[i*12 + c] = w2[c*2000 + i]
// ---------------------------------------------------------------------------
__global__ __launch_bounds__(256) void w2t_kernel(const float* __restrict__ w2,
                                                  float* __restrict__ w2t) {
    int t = blockIdx.x * 256 + threadIdx.x;
    if (t < N_HID * 10) {
        int i = t / 10, c = t - i * 10;
        w2t[i * 12 + c] = w2[c * N_HID + i];
    }
}

// ---------------------------------------------------------------------------
// Phase 1: h = x @ W1^T + b1, fp32.  Round-4 version VERBATIM (best: 587 us).
// 128x128 tile, BK=16, 8x8 microtile (split 4+4), register-prefetch + LDS
// double-buffer, one __syncthreads per K-chunk.  Per-output k-order identical
// to rounds 2-5 -> h bit-identical.
// ---------------------------------------------------------------------------
__global__ __launch_bounds__(256) void gemm_fp32_kernel(const float* __restrict__ x,
                                                        const float* __restrict__ w1,
                                                        const float* __restrict__ b1,
                                                        float* __restrict__ h) {
    __shared__ float As[2][16][132] __attribute__((aligned(16)));   // [buf][k][m]
    __shared__ float Bs[2][16][132] __attribute__((aligned(16)));   // [buf][k][n]
    const int tid = threadIdx.x;
    const int n0 = blockIdx.x * 128;
    const int m0 = blockIdx.y * 128;
    const int tx = tid & 15;        // n microtile
    const int ty = tid >> 4;        // m microtile
    const int r  = tid >> 2;        // 0..63 staging row
    const int c  = (tid & 3) << 2;  // 0,4,8,12 staging k-offset

    const int nb0 = n0 + r;
    const int nb1 = (n0 + r + 64 < N_HID) ? (n0 + r + 64) : (N_HID - 1);

    const float* xp0 = x  + (size_t)(m0 + r)      * IN_DIM + c;
    const float* xp1 = x  + (size_t)(m0 + r + 64) * IN_DIM + c;
    const float* wp0 = w1 + (size_t)nb0           * IN_DIM + c;
    const float* wp1 = w1 + (size_t)nb1           * IN_DIM + c;

    float4 pa0 = *(const float4*)(xp0);
    float4 pa1 = *(const float4*)(xp1);
    float4 pb0 = *(const float4*)(wp0);
    float4 pb1 = *(const float4*)(wp1);

    float acc[8][8] = {};
    int buf = 0;

    for (int k0 = 0; k0 < IN_DIM; k0 += 16) {
        float (*A)[132] = As[buf];
        float (*Bv)[132] = Bs[buf];
        A[c + 0][r] = pa0.x;  A[c + 1][r] = pa0.y;  A[c + 2][r] = pa0.z;  A[c + 3][r] = pa0.w;
        A[c + 0][r + 64] = pa1.x;  A[c + 1][r + 64] = pa1.y;  A[c + 2][r + 64] = pa1.z;  A[c + 3][r + 64] = pa1.w;
        Bv[c + 0][r] = pb0.x;  Bv[c + 1][r] = pb0.y;  Bv[c + 2][r] = pb0.z;  Bv[c + 3][r] = pb0.w;
        Bv[c + 0][r + 64] = pb1.x; Bv[c + 1][r + 64] = pb1.y; Bv[c + 2][r + 64] = pb1.z; Bv[c + 3][r + 64] = pb1.w;
        __syncthreads();

        const int kn = (k0 + 16 < IN_DIM) ? (k0 + 16) : 0;  // last-iter dummy
        pa0 = *(const float4*)(xp0 + kn);
        pa1 = *(const float4*)(xp1 + kn);
        pb0 = *(const float4*)(wp0 + kn);
        pb1 = *(const float4*)(wp1 + kn);

        #pragma unroll
        for (int kk = 0; kk < 16; ++kk) {
            float a[8], b[8];
            *(float4*)&a[0] = *(const float4*)&A[kk][ty * 4];
            *(float4*)&a[4] = *(const float4*)&A[kk][64 + ty * 4];
            *(float4*)&b[0] = *(const float4*)&Bv[kk][tx * 4];
            *(float4*)&b[4] = *(const float4*)&Bv[kk][64 + tx * 4];
            #pragma unroll
            for (int i = 0; i < 8; ++i)
                #pragma unroll
                for (int j = 0; j < 8; ++j)
                    acc[i][j] = fmaf(a[i], b[j], acc[i][j]);
        }
        buf ^= 1;
    }

    const int nlo = n0 + tx * 4;        // <= 1983: unguarded
    const int nhi = n0 + 64 + tx * 4;   // may exceed: guarded
    #pragma unroll
    for (int i = 0; i < 8; ++i) {
        const int m = m0 + ((i < 4) ? (ty * 4 + i) : (64 + ty * 4 + (i - 4)));
        float* hrow = h + (size_t)m * N_HID;
        float4 v;
        v.x = acc[i][0] + b1[nlo + 0];
        v.y = acc[i][1] + b1[nlo + 1];
        v.z = acc[i][2] + b1[nlo + 2];
        v.w = acc[i][3] + b1[nlo + 3];
        *(float4*)(hrow + nlo) = v;
        if (nhi + 3 < N_HID) {
            float4 w;
            w.x = acc[i][4] + b1[nhi + 0];
            w.y = acc[i][5] + b1[nhi + 1];
            w.z = acc[i][6] + b1[nhi + 2];
            w.w = acc[i][7] + b1[nhi + 3];
            *(float4*)(hrow + nhi) = w;
        } else {
            #pragma unroll
            for (int j = 0; j < 4; ++j)
                if (nhi + j < N_HID) hrow[nhi + j] = acc[i][4 + j] + b1[nhi + j];
        }
    }
}

// ---------------------------------------------------------------------------
// Phase 2a: per-row threshold.  One row per wave, 4 rows/block, zero
// __syncthreads.  Builds monotone u32 keys of h*boost, 4-pass byte radix
// select; writes (tkey, take_eq) per row.  Key math identical to rounds 3-5.
// ---------------------------------------------------------------------------
__global__ __launch_bounds__(256) void thresh_kernel(const float* __restrict__ h,
                                                     const float* __restrict__ boost,
                                                     uint2* __restrict__ rowinfo) {
    __shared__ unsigned shist[4 * 256] __attribute__((aligned(16)));
    const int wv   = threadIdx.x >> 6;
    const int lane = threadIdx.x & 63;
    const int row  = blockIdx.x * 4 + wv;
    unsigned* hist = &shist[wv * 256];

    const float* hrow = h + (size_t)row * N_HID;
    unsigned key[8][4];

    #pragma unroll
    for (int s = 0; s < 8; ++s) {
        const int idx4 = s * 64 + lane;
        if (idx4 < N_HID / 4) {
            float4 hv = *(const float4*)(hrow + idx4 * 4);
            float4 bv = *(const float4*)(boost + idx4 * 4);
            unsigned u0 = __float_as_uint(hv.x * bv.x);
            unsigned u1 = __float_as_uint(hv.y * bv.y);
            unsigned u2 = __float_as_uint(hv.z * bv.z);
            unsigned u3 = __float_as_uint(hv.w * bv.w);
            key[s][0] = (u0 >> 31) ? ~u0 : (u0 | 0x80000000u);
            key[s][1] = (u1 >> 31) ? ~u1 : (u1 | 0x80000000u);
            key[s][2] = (u2 >> 31) ? ~u2 : (u2 | 0x80000000u);
            key[s][3] = (u3 >> 31) ? ~u3 : (u3 | 0x80000000u);
        } else {
            key[s][0] = key[s][1] = key[s][2] = key[s][3] = 0u;
        }
    }

    unsigned pref = 0u;
    int r = K_WIN;

    #pragma unroll
    for (int pass = 3; pass >= 0; --pass) {
        const int shift = pass * 8;
        const unsigned himask = (pass == 3) ? 0u : (0xFFFFFFFFu << (shift + 8));
        hist[lane] = 0u; hist[lane + 64] = 0u; hist[lane + 128] = 0u; hist[lane + 192] = 0u;
        __builtin_amdgcn_wave_barrier();
        #pragma unroll
        for (int s = 0; s < 8; ++s)
            #pragma unroll
            for (int j = 0; j < 4; ++j) {
                unsigned k = key[s][j];
                if (((k ^ pref) & himask) == 0u)
                    atomicAdd(&hist[(k >> shift) & 255u], 1u);
            }
        __builtin_amdgcn_wave_barrier();
        uint4 hv = *(const uint4*)&hist[lane * 4];
        unsigned tot = hv.x + hv.y + hv.z + hv.w;
        unsigned run = tot;
        #pragma unroll
        for (int off = 1; off < 64; off <<= 1) {
            unsigned t = (unsigned)__shfl_down((int)run, off);
            if (lane + off < 64) run += t;
        }
        const int above = (int)(run - tot);
        const int i3 = above + (int)hv.w;
        const int i2 = i3 + (int)hv.z;
        const int i1 = i2 + (int)hv.y;
        const int i0 = i1 + (int)hv.x;
        int fq = -1, fex = 0;
        if (i0 >= r && i1 < r)    { fq = 0; fex = i1; }
        if (i1 >= r && i2 < r)    { fq = 1; fex = i2; }
        if (i2 >= r && i3 < r)    { fq = 2; fex = i3; }
        if (i3 >= r && above < r) { fq = 3; fex = above; }
        unsigned long long fm = __ballot(fq >= 0);
        int src = __builtin_ctzll(fm);
        unsigned pack = (fq >= 0)
            ? (((unsigned)(lane * 4 + fq) << 16) | (unsigned)(r - fex)) : 0u;
        pack = (unsigned)__shfl((int)pack, src);
        pref |= (pack >> 16) << shift;
        r = (int)(pack & 0xFFFFu);
    }

    if (lane == 0) rowinfo[row] = make_uint2(pref, (unsigned)r);
}

// ---------------------------------------------------------------------------
// Phase 2b: streaming logits.  One row per wave, 4 rows/block.  Recomputes
// keys chunk-by-chunk (identical ops -> identical comparisons vs thresh),
// winner flags via ballot bookkeeping (lowest-index ties), accumulates
// logits immediately in the same per-lane ascending (s,j) fmaf order as
// rounds 3-5 -> bit-identical output.
// ---------------------------------------------------------------------------
__global__ __launch_bounds__(256) void logits_kernel(const float* __restrict__ h,
                                                     const float* __restrict__ boost,
                                                     const uint2* __restrict__ rowinfo,
                                                     const float* __restrict__ w2t,
                                                     const float* __restrict__ b2,
                                                     float* __restrict__ out) {
    const int wv   = threadIdx.x >> 6;
    const int lane = threadIdx.x & 63;
    const int row  = blockIdx.x * 4 + wv;

    const uint2 ri = rowinfo[row];
    const unsigned tkey = ri.x;
    const int take_eq = (int)ri.y;

    const float* hrow = h + (size_t)row * N_HID;

    float l[10];
    #pragma unroll
    for (int cc = 0; cc < 10; ++cc) l[cc] = 0.f;
    int run_eq = 0;

    #pragma unroll
    for (int s = 0; s < 8; ++s) {
        const int idx4 = s * 64 + lane;
        float4 hv = make_float4(0.f, 0.f, 0.f, 0.f);
        unsigned k[4] = {0u, 0u, 0u, 0u};
        if (idx4 < N_HID / 4) {
            hv = *(const float4*)(hrow + idx4 * 4);
            float4 bv = *(const float4*)(boost + idx4 * 4);
            unsigned u0 = __float_as_uint(hv.x * bv.x);
            unsigned u1 = __float_as_uint(hv.y * bv.y);
            unsigned u2 = __float_as_uint(hv.z * bv.z);
            unsigned u3 = __float_as_uint(hv.w * bv.w);
            k[0] = (u0 >> 31) ? ~u0 : (u0 | 0x80000000u);
            k[1] = (u1 >> 31) ? ~u1 : (u1 | 0x80000000u);
            k[2] = (u2 >> 31) ? ~u2 : (u2 | 0x80000000u);
            k[3] = (u3 >> 31) ? ~u3 : (u3 | 0x80000000u);
        }
        bool gt[4], eq[4];
        #pragma unroll
        for (int j = 0; j < 4; ++j) {
            gt[j] = (k[j] > tkey);
            eq[j] = (k[j] == tkey);
        }
        unsigned long long em0 = __ballot(eq[0]);
        unsigned long long em1 = __ballot(eq[1]);
        unsigned long long em2 = __ballot(eq[2]);
        unsigned long long em3 = __ballot(eq[3]);
        const unsigned long long lt = (1ull << lane) - 1ull;
        const int base_lt = __popcll(em0 & lt) + __popcll(em1 & lt) +
                            __popcll(em2 & lt) + __popcll(em3 & lt);
        const float* hp = (const float*)&hv;
        int own = 0;
        #pragma unroll
        for (int j = 0; j < 4; ++j) {
            bool win = gt[j];
            if (eq[j]) {
                win = (run_eq + base_lt + own < take_eq);
                ++own;
            }
            if (win) {
                const float hvj = hp[j];
                const float* wr = w2t + (size_t)(idx4 * 4 + j) * 12;
                float4 wa = *(const float4*)wr;
                float4 wb = *(const float4*)(wr + 4);
                float2 wc = *(const float2*)(wr + 8);
                l[0] = fmaf(hvj, wa.x, l[0]);
                l[1] = fmaf(hvj, wa.y, l[1]);
                l[2] = fmaf(hvj, wa.z, l[2]);
                l[3] = fmaf(hvj, wa.w, l[3]);
                l[4] = fmaf(hvj, wb.x, l[4]);
                l[5] = fmaf(hvj, wb.y, l[5]);
                l[6] = fmaf(hvj, wb.z, l[6]);
                l[7] = fmaf(hvj, wb.w, l[7]);
                l[8] = fmaf(hvj, wc.x, l[8]);
                l[9] = fmaf(hvj, wc.y, l[9]);
            }
        }
        run_eq += __popcll(em0) + __popcll(em1) + __popcll(em2) + __popcll(em3);
    }

    #pragma unroll
    for (int off = 32; off > 0; off >>= 1)
        #pragma unroll
        for (int cc = 0; cc < 10; ++cc)
            l[cc] += __shfl_down(l[cc], off);

    if (lane == 0) {
        float lg[10];
        #pragma unroll
        for (int cc = 0; cc < 10; ++cc) lg[cc] = l[cc] + b2[cc];
        float mx = lg[0];
        #pragma unroll
        for (int cc = 1; cc < 10; ++cc) mx = fmaxf(mx, lg[cc]);
        float s = 0.f;
        #pragma unroll
        for (int cc = 0; cc < 10; ++cc) s += expf(lg[cc] - mx);
        const float lse = mx + logf(s);
        float* orow = out + (size_t)row * 10;
        #pragma unroll
        for (int cc = 0; cc < 10; ++cc) orow[cc] = lg[cc] - lse;
    }
}

// ---------------------------------------------------------------------------
extern "C" void kernel_launch(void* const* d_in, const int* in_sizes, int n_in,
                              void* d_out, int out_size, void* d_ws, size_t ws_size,
                              hipStream_t stream) {
    const float* x    = (const float*)d_in[0];
    const float* w1   = (const float*)d_in[1];
    const float* b1   = (const float*)d_in[2];
    const float* w2   = (const float*)d_in[3];
    const float* b2   = (const float*)d_in[4];
    const float* duty = (const float*)d_in[5];
    float* out = (float*)d_out;

    const size_t hbytes = (size_t)B_ROWS * N_HID * sizeof(float);      // 131.072 MB
    float* h       = (float*)d_ws;
    float* boost   = (float*)((char*)d_ws + hbytes);                   // 8 KB
    float* w2t     = (float*)((char*)d_ws + hbytes + 8192);            // 96 KB
    uint2* rowinfo = (uint2*)((char*)d_ws + hbytes + 8192 + 96000);    // 128 KB

    boost_kernel<<<8, 256, 0, stream>>>(duty, boost);
    w2t_kernel<<<(N_HID * 10 + 255) / 256, 256, 0, stream>>>(w2, w2t);
    gemm_fp32_kernel<<<dim3(16, 128), 256, 0, stream>>>(x, w1, b1, h);
    thresh_kernel<<<B_ROWS / 4, 256, 0, stream>>>(h, boost, rowinfo);
    logits_kernel<<<B_ROWS / 4, 256, 0, stream>>>(h, boost, rowinfo, w2t, b2, out);
}

// Round 7
// 755.838 us; speedup vs baseline: 1.0464x; 1.0250x over previous
//
#include <hip/hip_runtime.h>
#include <cmath>

#define B_ROWS 16384
#define IN_DIM 784
#define N_HID  2000
#define K_WIN  200

// Replicated histogram geometry: 8 replicas per wave, stride 260 words.
// bank(bin b, replica r) = (b + 4r) % 32 -> all 8 replicas of a bin hit
// DIFFERENT banks (parallel atomics); 260*4 % 16 == 0 keeps uint4 alignment.
#define HREP   8
#define HSTRIDE 260
#define HWAVE  (HREP * HSTRIDE)   // 2080 words per wave

// ---------------------------------------------------------------------------
// Phase 0a: boost[i] = expf(0.1f - duty[i])
// ---------------------------------------------------------------------------
__global__ __launch_bounds__(256) void boost_kernel(const float* __restrict__ duty,
                                                    float* __restrict__ boost) {
    int i = blockIdx.x * 256 + threadIdx.x;
    if (i < N_HID) boost[i] = expf(0.1f - duty[i]);
}

// ---------------------------------------------------------------------------
// Phase 0b: w2t[i*12 + c] = w2[c*2000 + i]
// ---------------------------------------------------------------------------
__global__ __launch_bounds__(256) void w2t_kernel(const float* __restrict__ w2,
                                                  float* __restrict__ w2t) {
    int t = blockIdx.x * 256 + threadIdx.x;
    if (t < N_HID * 10) {
        int i = t / 10, c = t - i * 10;
        w2t[i * 12 + c] = w2[c * N_HID + i];
    }
}

// ---------------------------------------------------------------------------
// Phase 1: h = x @ W1^T + b1, fp32.  Round-4 version VERBATIM (best: 587 us).
// ---------------------------------------------------------------------------
__global__ __launch_bounds__(256) void gemm_fp32_kernel(const float* __restrict__ x,
                                                        const float* __restrict__ w1,
                                                        const float* __restrict__ b1,
                                                        float* __restrict__ h) {
    __shared__ float As[2][16][132] __attribute__((aligned(16)));   // [buf][k][m]
    __shared__ float Bs[2][16][132] __attribute__((aligned(16)));   // [buf][k][n]
    const int tid = threadIdx.x;
    const int n0 = blockIdx.x * 128;
    const int m0 = blockIdx.y * 128;
    const int tx = tid & 15;
    const int ty = tid >> 4;
    const int r  = tid >> 2;
    const int c  = (tid & 3) << 2;

    const int nb0 = n0 + r;
    const int nb1 = (n0 + r + 64 < N_HID) ? (n0 + r + 64) : (N_HID - 1);

    const float* xp0 = x  + (size_t)(m0 + r)      * IN_DIM + c;
    const float* xp1 = x  + (size_t)(m0 + r + 64) * IN_DIM + c;
    const float* wp0 = w1 + (size_t)nb0           * IN_DIM + c;
    const float* wp1 = w1 + (size_t)nb1           * IN_DIM + c;

    float4 pa0 = *(const float4*)(xp0);
    float4 pa1 = *(const float4*)(xp1);
    float4 pb0 = *(const float4*)(wp0);
    float4 pb1 = *(const float4*)(wp1);

    float acc[8][8] = {};
    int buf = 0;

    for (int k0 = 0; k0 < IN_DIM; k0 += 16) {
        float (*A)[132] = As[buf];
        float (*Bv)[132] = Bs[buf];
        A[c + 0][r] = pa0.x;  A[c + 1][r] = pa0.y;  A[c + 2][r] = pa0.z;  A[c + 3][r] = pa0.w;
        A[c + 0][r + 64] = pa1.x;  A[c + 1][r + 64] = pa1.y;  A[c + 2][r + 64] = pa1.z;  A[c + 3][r + 64] = pa1.w;
        Bv[c + 0][r] = pb0.x;  Bv[c + 1][r] = pb0.y;  Bv[c + 2][r] = pb0.z;  Bv[c + 3][r] = pb0.w;
        Bv[c + 0][r + 64] = pb1.x; Bv[c + 1][r + 64] = pb1.y; Bv[c + 2][r + 64] = pb1.z; Bv[c + 3][r + 64] = pb1.w;
        __syncthreads();

        const int kn = (k0 + 16 < IN_DIM) ? (k0 + 16) : 0;
        pa0 = *(const float4*)(xp0 + kn);
        pa1 = *(const float4*)(xp1 + kn);
        pb0 = *(const float4*)(wp0 + kn);
        pb1 = *(const float4*)(wp1 + kn);

        #pragma unroll
        for (int kk = 0; kk < 16; ++kk) {
            float a[8], b[8];
            *(float4*)&a[0] = *(const float4*)&A[kk][ty * 4];
            *(float4*)&a[4] = *(const float4*)&A[kk][64 + ty * 4];
            *(float4*)&b[0] = *(const float4*)&Bv[kk][tx * 4];
            *(float4*)&b[4] = *(const float4*)&Bv[kk][64 + tx * 4];
            #pragma unroll
            for (int i = 0; i < 8; ++i)
                #pragma unroll
                for (int j = 0; j < 8; ++j)
                    acc[i][j] = fmaf(a[i], b[j], acc[i][j]);
        }
        buf ^= 1;
    }

    const int nlo = n0 + tx * 4;
    const int nhi = n0 + 64 + tx * 4;
    #pragma unroll
    for (int i = 0; i < 8; ++i) {
        const int m = m0 + ((i < 4) ? (ty * 4 + i) : (64 + ty * 4 + (i - 4)));
        float* hrow = h + (size_t)m * N_HID;
        float4 v;
        v.x = acc[i][0] + b1[nlo + 0];
        v.y = acc[i][1] + b1[nlo + 1];
        v.z = acc[i][2] + b1[nlo + 2];
        v.w = acc[i][3] + b1[nlo + 3];
        *(float4*)(hrow + nlo) = v;
        if (nhi + 3 < N_HID) {
            float4 w;
            w.x = acc[i][4] + b1[nhi + 0];
            w.y = acc[i][5] + b1[nhi + 1];
            w.z = acc[i][6] + b1[nhi + 2];
            w.w = acc[i][7] + b1[nhi + 3];
            *(float4*)(hrow + nhi) = w;
        } else {
            #pragma unroll
            for (int j = 0; j < 4; ++j)
                if (nhi + j < N_HID) hrow[nhi + j] = acc[i][4 + j] + b1[nhi + j];
        }
    }
}

// ---------------------------------------------------------------------------
// Phase 2: monolithic (round-4 structure) with 8-WAY REPLICATED HISTOGRAMS.
// One row per wave, 4 rows/block, zero __syncthreads.  Replication breaks
// the same-bin LDS-atomic serialization caused by exponent clustering of
// N(0,1) keys (up to 64-way -> max 8-way, and the 8 replicas of a bin live
// in different banks so they proceed in parallel).
// ---------------------------------------------------------------------------
__global__ __launch_bounds__(256) void topk_logits_kernel(const float* __restrict__ h,
                                                          const float* __restrict__ boost,
                                                          const float* __restrict__ w2t,
                                                          const float* __restrict__ b2,
                                                          float* __restrict__ out) {
    __shared__ unsigned shist[4 * HWAVE] __attribute__((aligned(16)));
    const int wv   = threadIdx.x >> 6;
    const int lane = threadIdx.x & 63;
    const int row  = blockIdx.x * 4 + wv;
    unsigned* hist = &shist[wv * HWAVE];
    const int rep  = lane & (HREP - 1);

    const float* hrow = h + (size_t)row * N_HID;
    float4 hreg[8];
    unsigned key[8][4];

    #pragma unroll
    for (int s = 0; s < 8; ++s) {
        const int idx4 = s * 64 + lane;
        if (idx4 < N_HID / 4) {
            float4 hv = *(const float4*)(hrow + idx4 * 4);
            float4 bv = *(const float4*)(boost + idx4 * 4);
            hreg[s] = hv;
            unsigned u0 = __float_as_uint(hv.x * bv.x);
            unsigned u1 = __float_as_uint(hv.y * bv.y);
            unsigned u2 = __float_as_uint(hv.z * bv.z);
            unsigned u3 = __float_as_uint(hv.w * bv.w);
            key[s][0] = (u0 >> 31) ? ~u0 : (u0 | 0x80000000u);
            key[s][1] = (u1 >> 31) ? ~u1 : (u1 | 0x80000000u);
            key[s][2] = (u2 >> 31) ? ~u2 : (u2 | 0x80000000u);
            key[s][3] = (u3 >> 31) ? ~u3 : (u3 | 0x80000000u);
        } else {
            hreg[s] = make_float4(0.f, 0.f, 0.f, 0.f);
            key[s][0] = key[s][1] = key[s][2] = key[s][3] = 0u;
        }
    }

    unsigned pref = 0u;
    int r = K_WIN;

    #pragma unroll
    for (int pass = 3; pass >= 0; --pass) {
        const int shift = pass * 8;
        const unsigned himask = (pass == 3) ? 0u : (0xFFFFFFFFu << (shift + 8));
        // zero all replicas (520 uint4 per wave)
        {
            uint4 z = make_uint4(0u, 0u, 0u, 0u);
            uint4* hb = (uint4*)hist;
            #pragma unroll
            for (int i = 0; i < HWAVE / 4; i += 64)
                if (i + lane < HWAVE / 4) hb[i + lane] = z;
        }
        __builtin_amdgcn_wave_barrier();
        #pragma unroll
        for (int s = 0; s < 8; ++s)
            #pragma unroll
            for (int j = 0; j < 4; ++j) {
                unsigned k = key[s][j];
                if (((k ^ pref) & himask) == 0u)
                    atomicAdd(&hist[rep * HSTRIDE + ((k >> shift) & 255u)], 1u);
            }
        __builtin_amdgcn_wave_barrier();
        // merge replicas for bins 4*lane .. 4*lane+3, then suffix-scan
        uint4 hv = make_uint4(0u, 0u, 0u, 0u);
        #pragma unroll
        for (int q = 0; q < HREP; ++q) {
            uint4 u = *(const uint4*)&hist[q * HSTRIDE + lane * 4];
            hv.x += u.x; hv.y += u.y; hv.z += u.z; hv.w += u.w;
        }
        unsigned tot = hv.x + hv.y + hv.z + hv.w;
        unsigned run = tot;
        #pragma unroll
        for (int off = 1; off < 64; off <<= 1) {
            unsigned t = (unsigned)__shfl_down((int)run, off);
            if (lane + off < 64) run += t;
        }
        const int above = (int)(run - tot);
        const int i3 = above + (int)hv.w;
        const int i2 = i3 + (int)hv.z;
        const int i1 = i2 + (int)hv.y;
        const int i0 = i1 + (int)hv.x;
        int fq = -1, fex = 0;
        if (i0 >= r && i1 < r)    { fq = 0; fex = i1; }
        if (i1 >= r && i2 < r)    { fq = 1; fex = i2; }
        if (i2 >= r && i3 < r)    { fq = 2; fex = i3; }
        if (i3 >= r && above < r) { fq = 3; fex = above; }
        unsigned long long fm = __ballot(fq >= 0);
        int src = __builtin_ctzll(fm);
        unsigned pack = (fq >= 0)
            ? (((unsigned)(lane * 4 + fq) << 16) | (unsigned)(r - fex)) : 0u;
        pack = (unsigned)__shfl((int)pack, src);
        pref |= (pack >> 16) << shift;
        r = (int)(pack & 0xFFFFu);
    }

    const unsigned tkey = pref;
    const int take_eq = r;

    unsigned winm = 0u;
    int run_eq = 0;
    #pragma unroll
    for (int s = 0; s < 8; ++s) {
        bool gt[4], eq[4];
        #pragma unroll
        for (int j = 0; j < 4; ++j) {
            unsigned k = key[s][j];
            gt[j] = (k > tkey);
            eq[j] = (k == tkey);
        }
        unsigned long long em0 = __ballot(eq[0]);
        unsigned long long em1 = __ballot(eq[1]);
        unsigned long long em2 = __ballot(eq[2]);
        unsigned long long em3 = __ballot(eq[3]);
        const unsigned long long lt = (1ull << lane) - 1ull;
        const int base_lt = __popcll(em0 & lt) + __popcll(em1 & lt) +
                            __popcll(em2 & lt) + __popcll(em3 & lt);
        int own = 0;
        #pragma unroll
        for (int j = 0; j < 4; ++j) {
            if (gt[j]) winm |= 1u << (s * 4 + j);
            else if (eq[j]) {
                if (run_eq + base_lt + own < take_eq) winm |= 1u << (s * 4 + j);
                ++own;
            }
        }
        run_eq += __popcll(em0) + __popcll(em1) + __popcll(em2) + __popcll(em3);
    }

    float l[10];
    #pragma unroll
    for (int cc = 0; cc < 10; ++cc) l[cc] = 0.f;
    #pragma unroll
    for (int s = 0; s < 8; ++s) {
        const int idx4 = s * 64 + lane;
        const float* hp = (const float*)&hreg[s];
        #pragma unroll
        for (int j = 0; j < 4; ++j) {
            if (winm & (1u << (s * 4 + j))) {
                const float hv = hp[j];
                const float* wr = w2t + (size_t)(idx4 * 4 + j) * 12;
                float4 wa = *(const float4*)wr;
                float4 wb = *(const float4*)(wr + 4);
                float2 wc = *(const float2*)(wr + 8);
                l[0] = fmaf(hv, wa.x, l[0]);
                l[1] = fmaf(hv, wa.y, l[1]);
                l[2] = fmaf(hv, wa.z, l[2]);
                l[3] = fmaf(hv, wa.w, l[3]);
                l[4] = fmaf(hv, wb.x, l[4]);
                l[5] = fmaf(hv, wb.y, l[5]);
                l[6] = fmaf(hv, wb.z, l[6]);
                l[7] = fmaf(hv, wb.w, l[7]);
                l[8] = fmaf(hv, wc.x, l[8]);
                l[9] = fmaf(hv, wc.y, l[9]);
            }
        }
    }
    #pragma unroll
    for (int off = 32; off > 0; off >>= 1)
        #pragma unroll
        for (int cc = 0; cc < 10; ++cc)
            l[cc] += __shfl_down(l[cc], off);

    if (lane == 0) {
        float lg[10];
        #pragma unroll
        for (int cc = 0; cc < 10; ++cc) lg[cc] = l[cc] + b2[cc];
        float mx = lg[0];
        #pragma unroll
        for (int cc = 1; cc < 10; ++cc) mx = fmaxf(mx, lg[cc]);
        float s = 0.f;
        #pragma unroll
        for (int cc = 0; cc < 10; ++cc) s += expf(lg[cc] - mx);
        const float lse = mx + logf(s);
        float* orow = out + (size_t)row * 10;
        #pragma unroll
        for (int cc = 0; cc < 10; ++cc) orow[cc] = lg[cc] - lse;
    }
}

// ---------------------------------------------------------------------------
extern "C" void kernel_launch(void* const* d_in, const int* in_sizes, int n_in,
                              void* d_out, int out_size, void* d_ws, size_t ws_size,
                              hipStream_t stream) {
    const float* x    = (const float*)d_in[0];
    const float* w1   = (const float*)d_in[1];
    const float* b1   = (const float*)d_in[2];
    const float* w2   = (const float*)d_in[3];
    const float* b2   = (const float*)d_in[4];
    const float* duty = (const float*)d_in[5];
    float* out = (float*)d_out;

    const size_t hbytes = (size_t)B_ROWS * N_HID * sizeof(float);  // 131.072 MB
    float* h     = (float*)d_ws;
    float* boost = (float*)((char*)d_ws + hbytes);                 // 8 KB
    float* w2t   = (float*)((char*)d_ws + hbytes + 8192);          // 96 KB

    boost_kernel<<<8, 256, 0, stream>>>(duty, boost);
    w2t_kernel<<<(N_HID * 10 + 255) / 256, 256, 0, stream>>>(w2, w2t);
    gemm_fp32_kernel<<<dim3(16, 128), 256, 0, stream>>>(x, w1, b1, h);
    topk_logits_kernel<<<B_ROWS / 4, 256, 0, stream>>>(h, boost, w2t, b2, out);
}

// Round 8
// 720.845 us; speedup vs baseline: 1.0972x; 1.0485x over previous
//
#include <hip/hip_runtime.h>
#include <cmath>

#define B_ROWS 16384
#define IN_DIM 784
#define N_HID  2000
#define K_WIN  200

// ---------------------------------------------------------------------------
// Phase 0a: boost[i] = expf(0.1f - duty[i])
// ---------------------------------------------------------------------------
__global__ __launch_bounds__(256) void boost_kernel(const float* __restrict__ duty,
                                                    float* __restrict__ boost) {
    int i = blockIdx.x * 256 + threadIdx.x;
    if (i < N_HID) boost[i] = expf(0.1f - duty[i]);
}

// ---------------------------------------------------------------------------
// Phase 0b: w2t[i*12 + c] = w2[c*2000 + i]
// ---------------------------------------------------------------------------
__global__ __launch_bounds__(256) void w2t_kernel(const float* __restrict__ w2,
                                                  float* __restrict__ w2t) {
    int t = blockIdx.x * 256 + threadIdx.x;
    if (t < N_HID * 10) {
        int i = t / 10, c = t - i * 10;
        w2t[i * 12 + c] = w2[c * N_HID + i];
    }
}

// ---------------------------------------------------------------------------
// Phase 1: h = x @ W1^T + b1, fp32.  Round-4 version VERBATIM (best: 587 us).
// ---------------------------------------------------------------------------
__global__ __launch_bounds__(256) void gemm_fp32_kernel(const float* __restrict__ x,
                                                        const float* __restrict__ w1,
                                                        const float* __restrict__ b1,
                                                        float* __restrict__ h) {
    __shared__ float As[2][16][132] __attribute__((aligned(16)));   // [buf][k][m]
    __shared__ float Bs[2][16][132] __attribute__((aligned(16)));   // [buf][k][n]
    const int tid = threadIdx.x;
    const int n0 = blockIdx.x * 128;
    const int m0 = blockIdx.y * 128;
    const int tx = tid & 15;
    const int ty = tid >> 4;
    const int r  = tid >> 2;
    const int c  = (tid & 3) << 2;

    const int nb0 = n0 + r;
    const int nb1 = (n0 + r + 64 < N_HID) ? (n0 + r + 64) : (N_HID - 1);

    const float* xp0 = x  + (size_t)(m0 + r)      * IN_DIM + c;
    const float* xp1 = x  + (size_t)(m0 + r + 64) * IN_DIM + c;
    const float* wp0 = w1 + (size_t)nb0           * IN_DIM + c;
    const float* wp1 = w1 + (size_t)nb1           * IN_DIM + c;

    float4 pa0 = *(const float4*)(xp0);
    float4 pa1 = *(const float4*)(xp1);
    float4 pb0 = *(const float4*)(wp0);
    float4 pb1 = *(const float4*)(wp1);

    float acc[8][8] = {};
    int buf = 0;

    for (int k0 = 0; k0 < IN_DIM; k0 += 16) {
        float (*A)[132] = As[buf];
        float (*Bv)[132] = Bs[buf];
        A[c + 0][r] = pa0.x;  A[c + 1][r] = pa0.y;  A[c + 2][r] = pa0.z;  A[c + 3][r] = pa0.w;
        A[c + 0][r + 64] = pa1.x;  A[c + 1][r + 64] = pa1.y;  A[c + 2][r + 64] = pa1.z;  A[c + 3][r + 64] = pa1.w;
        Bv[c + 0][r] = pb0.x;  Bv[c + 1][r] = pb0.y;  Bv[c + 2][r] = pb0.z;  Bv[c + 3][r] = pb0.w;
        Bv[c + 0][r + 64] = pb1.x; Bv[c + 1][r + 64] = pb1.y; Bv[c + 2][r + 64] = pb1.z; Bv[c + 3][r + 64] = pb1.w;
        __syncthreads();

        const int kn = (k0 + 16 < IN_DIM) ? (k0 + 16) : 0;
        pa0 = *(const float4*)(xp0 + kn);
        pa1 = *(const float4*)(xp1 + kn);
        pb0 = *(const float4*)(wp0 + kn);
        pb1 = *(const float4*)(wp1 + kn);

        #pragma unroll
        for (int kk = 0; kk < 16; ++kk) {
            float a[8], b[8];
            *(float4*)&a[0] = *(const float4*)&A[kk][ty * 4];
            *(float4*)&a[4] = *(const float4*)&A[kk][64 + ty * 4];
            *(float4*)&b[0] = *(const float4*)&Bv[kk][tx * 4];
            *(float4*)&b[4] = *(const float4*)&Bv[kk][64 + tx * 4];
            #pragma unroll
            for (int i = 0; i < 8; ++i)
                #pragma unroll
                for (int j = 0; j < 8; ++j)
                    acc[i][j] = fmaf(a[i], b[j], acc[i][j]);
        }
        buf ^= 1;
    }

    const int nlo = n0 + tx * 4;
    const int nhi = n0 + 64 + tx * 4;
    #pragma unroll
    for (int i = 0; i < 8; ++i) {
        const int m = m0 + ((i < 4) ? (ty * 4 + i) : (64 + ty * 4 + (i - 4)));
        float* hrow = h + (size_t)m * N_HID;
        float4 v;
        v.x = acc[i][0] + b1[nlo + 0];
        v.y = acc[i][1] + b1[nlo + 1];
        v.z = acc[i][2] + b1[nlo + 2];
        v.w = acc[i][3] + b1[nlo + 3];
        *(float4*)(hrow + nlo) = v;
        if (nhi + 3 < N_HID) {
            float4 w;
            w.x = acc[i][4] + b1[nhi + 0];
            w.y = acc[i][5] + b1[nhi + 1];
            w.z = acc[i][6] + b1[nhi + 2];
            w.w = acc[i][7] + b1[nhi + 3];
            *(float4*)(hrow + nhi) = w;
        } else {
            #pragma unroll
            for (int j = 0; j < 4; ++j)
                if (nhi + j < N_HID) hrow[nhi + j] = acc[i][4 + j] + b1[nhi + j];
        }
    }
}

// ---------------------------------------------------------------------------
// Phase 2: one row per wave, 4 rows/block, zero __syncthreads.
// Radix select identical to round 4 (simple per-wave histograms).  NEW:
// the exactly-K_WIN winners are COMPACTED into LDS (position from the ballot
// masks already computed for tie-breaking), then gathered in a uniform
// 4-iteration unrolled loop -> w2t L2 latencies overlap instead of 32
// serialized divergent-branch gathers.  Winner SET identical to rounds 3-7;
// only the lane-partition of the 200-term logit sum changes (+-1 ulp).
// ---------------------------------------------------------------------------
__global__ __launch_bounds__(256) void topk_logits_kernel(const float* __restrict__ h,
                                                          const float* __restrict__ boost,
                                                          const float* __restrict__ w2t,
                                                          const float* __restrict__ b2,
                                                          float* __restrict__ out) {
    __shared__ unsigned shist[4 * 256] __attribute__((aligned(16)));
    __shared__ uint2 swin[4][K_WIN] __attribute__((aligned(16)));
    const int wv   = threadIdx.x >> 6;
    const int lane = threadIdx.x & 63;
    const int row  = blockIdx.x * 4 + wv;
    unsigned* hist = &shist[wv * 256];

    const float* hrow = h + (size_t)row * N_HID;
    float4 hreg[8];
    unsigned key[8][4];

    #pragma unroll
    for (int s = 0; s < 8; ++s) {
        const int idx4 = s * 64 + lane;
        if (idx4 < N_HID / 4) {
            float4 hv = *(const float4*)(hrow + idx4 * 4);
            float4 bv = *(const float4*)(boost + idx4 * 4);
            hreg[s] = hv;
            unsigned u0 = __float_as_uint(hv.x * bv.x);
            unsigned u1 = __float_as_uint(hv.y * bv.y);
            unsigned u2 = __float_as_uint(hv.z * bv.z);
            unsigned u3 = __float_as_uint(hv.w * bv.w);
            key[s][0] = (u0 >> 31) ? ~u0 : (u0 | 0x80000000u);
            key[s][1] = (u1 >> 31) ? ~u1 : (u1 | 0x80000000u);
            key[s][2] = (u2 >> 31) ? ~u2 : (u2 | 0x80000000u);
            key[s][3] = (u3 >> 31) ? ~u3 : (u3 | 0x80000000u);
        } else {
            hreg[s] = make_float4(0.f, 0.f, 0.f, 0.f);
            key[s][0] = key[s][1] = key[s][2] = key[s][3] = 0u;
        }
    }

    unsigned pref = 0u;
    int r = K_WIN;

    #pragma unroll
    for (int pass = 3; pass >= 0; --pass) {
        const int shift = pass * 8;
        const unsigned himask = (pass == 3) ? 0u : (0xFFFFFFFFu << (shift + 8));
        hist[lane] = 0u; hist[lane + 64] = 0u; hist[lane + 128] = 0u; hist[lane + 192] = 0u;
        __builtin_amdgcn_wave_barrier();
        #pragma unroll
        for (int s = 0; s < 8; ++s)
            #pragma unroll
            for (int j = 0; j < 4; ++j) {
                unsigned k = key[s][j];
                if (((k ^ pref) & himask) == 0u)
                    atomicAdd(&hist[(k >> shift) & 255u], 1u);
            }
        __builtin_amdgcn_wave_barrier();
        uint4 hv = *(const uint4*)&hist[lane * 4];
        unsigned tot = hv.x + hv.y + hv.z + hv.w;
        unsigned run = tot;
        #pragma unroll
        for (int off = 1; off < 64; off <<= 1) {
            unsigned t = (unsigned)__shfl_down((int)run, off);
            if (lane + off < 64) run += t;
        }
        const int above = (int)(run - tot);
        const int i3 = above + (int)hv.w;
        const int i2 = i3 + (int)hv.z;
        const int i1 = i2 + (int)hv.y;
        const int i0 = i1 + (int)hv.x;
        int fq = -1, fex = 0;
        if (i0 >= r && i1 < r)    { fq = 0; fex = i1; }
        if (i1 >= r && i2 < r)    { fq = 1; fex = i2; }
        if (i2 >= r && i3 < r)    { fq = 2; fex = i3; }
        if (i3 >= r && above < r) { fq = 3; fex = above; }
        unsigned long long fm = __ballot(fq >= 0);
        int src = __builtin_ctzll(fm);
        unsigned pack = (fq >= 0)
            ? (((unsigned)(lane * 4 + fq) << 16) | (unsigned)(r - fex)) : 0u;
        pack = (unsigned)__shfl((int)pack, src);
        pref |= (pack >> 16) << shift;
        r = (int)(pack & 0xFFFFu);
    }

    const unsigned tkey = pref;
    const int take_eq = r;

    // Winner identification (identical tie-break) + LDS compaction.
    // Position of a winner = #winners with smaller index, from ballot masks.
    int base = 0;      // winners in slots processed so far
    int run_eq = 0;
    #pragma unroll
    for (int s = 0; s < 8; ++s) {
        const int idx4 = s * 64 + lane;
        const float* hp = (const float*)&hreg[s];
        bool gt[4], eq[4];
        #pragma unroll
        for (int j = 0; j < 4; ++j) {
            unsigned k = key[s][j];
            gt[j] = (k > tkey);
            eq[j] = (k == tkey);
        }
        unsigned long long em0 = __ballot(eq[0]);
        unsigned long long em1 = __ballot(eq[1]);
        unsigned long long em2 = __ballot(eq[2]);
        unsigned long long em3 = __ballot(eq[3]);
        const unsigned long long lt = (1ull << lane) - 1ull;
        const int base_lt = __popcll(em0 & lt) + __popcll(em1 & lt) +
                            __popcll(em2 & lt) + __popcll(em3 & lt);
        int own = 0;
        #pragma unroll
        for (int j = 0; j < 4; ++j) {
            bool win = gt[j];
            if (eq[j]) {
                win = (run_eq + base_lt + own < take_eq);
                ++own;
            }
            unsigned long long wm = __ballot(win);
            if (win) {
                const int pos = base + __popcll(wm & lt);
                swin[wv][pos] = make_uint2((unsigned)(idx4 * 4 + j),
                                           __float_as_uint(hp[j]));
            }
            base += __popcll(wm);
        }
        run_eq += __popcll(em0) + __popcll(em1) + __popcll(em2) + __popcll(em3);
    }
    __builtin_amdgcn_wave_barrier();

    // Uniform gather: exactly K_WIN winners; lane t*64+lane positions.
    float l[10];
    #pragma unroll
    for (int cc = 0; cc < 10; ++cc) l[cc] = 0.f;
    #pragma unroll
    for (int t = 0; t < 4; ++t) {
        const bool act = (t < 3) || (lane < K_WIN - 192);
        if (act) {
            const uint2 wrec = swin[wv][t * 64 + lane];
            const float hv = __uint_as_float(wrec.y);
            const float* wr = w2t + (size_t)wrec.x * 12;
            float4 wa = *(const float4*)wr;
            float4 wb = *(const float4*)(wr + 4);
            float2 wc = *(const float2*)(wr + 8);
            l[0] = fmaf(hv, wa.x, l[0]);
            l[1] = fmaf(hv, wa.y, l[1]);
            l[2] = fmaf(hv, wa.z, l[2]);
            l[3] = fmaf(hv, wa.w, l[3]);
            l[4] = fmaf(hv, wb.x, l[4]);
            l[5] = fmaf(hv, wb.y, l[5]);
            l[6] = fmaf(hv, wb.z, l[6]);
            l[7] = fmaf(hv, wb.w, l[7]);
            l[8] = fmaf(hv, wc.x, l[8]);
            l[9] = fmaf(hv, wc.y, l[9]);
        }
    }
    #pragma unroll
    for (int off = 32; off > 0; off >>= 1)
        #pragma unroll
        for (int cc = 0; cc < 10; ++cc)
            l[cc] += __shfl_down(l[cc], off);

    if (lane == 0) {
        float lg[10];
        #pragma unroll
        for (int cc = 0; cc < 10; ++cc) lg[cc] = l[cc] + b2[cc];
        float mx = lg[0];
        #pragma unroll
        for (int cc = 1; cc < 10; ++cc) mx = fmaxf(mx, lg[cc]);
        float s = 0.f;
        #pragma unroll
        for (int cc = 0; cc < 10; ++cc) s += expf(lg[cc] - mx);
        const float lse = mx + logf(s);
        float* orow = out + (size_t)row * 10;
        #pragma unroll
        for (int cc = 0; cc < 10; ++cc) orow[cc] = lg[cc] - lse;
    }
}

// ---------------------------------------------------------------------------
extern "C" void kernel_launch(void* const* d_in, const int* in_sizes, int n_in,
                              void* d_out, int out_size, void* d_ws, size_t ws_size,
                              hipStream_t stream) {
    const float* x    = (const float*)d_in[0];
    const float* w1   = (const float*)d_in[1];
    const float* b1   = (const float*)d_in[2];
    const float* w2   = (const float*)d_in[3];
    const float* b2   = (const float*)d_in[4];
    const float* duty = (const float*)d_in[5];
    float* out = (float*)d_out;

    const size_t hbytes = (size_t)B_ROWS * N_HID * sizeof(float);  // 131.072 MB
    float* h     = (float*)d_ws;
    float* boost = (float*)((char*)d_ws + hbytes);                 // 8 KB
    float* w2t   = (float*)((char*)d_ws + hbytes + 8192);          // 96 KB

    boost_kernel<<<8, 256, 0, stream>>>(duty, boost);
    w2t_kernel<<<(N_HID * 10 + 255) / 256, 256, 0, stream>>>(w2, w2t);
    gemm_fp32_kernel<<<dim3(16, 128), 256, 0, stream>>>(x, w1, b1, h);
    topk_logits_kernel<<<B_ROWS / 4, 256, 0, stream>>>(h, boost, w2t, b2, out);
}